// Round 10
// baseline (143.946 us; speedup 1.0000x reference)
//
#include <hip/hip_runtime.h>
#include <math.h>

// Problem constants (fixed by the reference)
#define NB   256                 // graphs
#define NPG  256                 // nodes per graph
#define NN   (NB * NPG)          // 65536 nodes
#define NE   (NN * 16)           // 1048576 edges
#define EPG  (NE / NB)           // 4096 edges per graph
#define FD   128                 // F == H
#define NC   10
#define NSL  32                  // slices (1024 threads / 32 lanes-per-slice)
#define NEG_INF (-3.402823466e38f)

// Shared-memory layout for the fused per-graph block: ~161.9 KB <= 160 KiB.
struct SM {
    float hs[NPG][FD];          // 128 KB: dvv-prescaled features (in place across levels)
    int   rp[NPG + 4];          // local CSR row pointers
    float dvv[NPG];             // dinv of the CURRENT level (next level's written in gate)
    float sw[NPG];              // score matvec result / MLP h1
    float sf[NPG];              // score conv result (by node id) / MLP h2
    float svv[NPG];             // sort value staging / MLP logits
    float th[NPG];              // tanh(score) for kept
    float zacc[2 * FD];         // readout accumulator across levels
    int   si[NPG];              // CSR counts / sort index staging
    int   kept[NPG];            // kept flags / CSR scatter cursor
    int   anode[NPG];           // active list
    int   wsum[16];             // wave-scan partials
    float red_mx[16][FD];       // per-wave readout partials
    float red_sm[16][FD];
    unsigned char colb[EPG];    // edge src local ids (CSR-by-dst order), 4 KB
};

// Swizzled access to feature-quad q (16B) of row v: physical quad = q ^ (v&7).
__device__ __forceinline__ float4& hsq(SM& sm, int v, int q) {
    return *(float4*)&sm.hs[v][(q ^ (v & 7)) << 2];
}

// ---------------------------------------------------------------------------
// One pooling level, fully in-LDS. NACT = active node count (256/128/64).
// Precondition: hs rows of active nodes hold dvv-PRESCALED input features
// (dvv ⊙ x); dropped rows are zero; dvv[] = this level's dinv.
// GEMM: lane<->row mapping. Wave w (w < RG*4, RG=NACT/64): rows
// anode[(w%RG)*64+lane], col block (w/RG)*32. Distinct-address LDS reads;
// W read at wave-uniform (scalar) addresses.
// conv/readout: f4 = tid&31 (feature quad), s = tid>>5 (slice);
// slice s owns active indices i = c*32+s, c < NPS = NACT/32.
// ---------------------------------------------------------------------------
template <int NACT, bool LAST>
__device__ __forceinline__ void do_level(SM& sm,
                                         const float* __restrict__ Wmat,
                                         const float* __restrict__ bias,
                                         const float* __restrict__ Wp,
                                         const float* __restrict__ bpp,
                                         int tid) {
    constexpr int NPS = NACT / NSL;      // rows per slice (conv)
    constexpr int K   = NACT / 2;
    constexpr int TPN = 1024 / NACT;     // threads per node in score conv
    constexpr int RG  = NACT / 64;       // GEMM row groups (4/2/1)
    const int f4 = tid & 31;
    const int s  = tid >> 5;
    const int wv_ = tid >> 6, lane = tid & 63;

    // ---- GEMM phase A (read+accumulate): acc = hs[row] @ W[:, cb*32..+32)
    // hs already carries the dvv prescale (row scaling commutes with @W).
    float4 a4[8];
    int myrow = 0, cb = 0;
    const bool gact = (wv_ < RG * 4);
    if (gact) {
        cb = __builtin_amdgcn_readfirstlane(wv_ / RG);
        myrow = sm.anode[(wv_ % RG) * 64 + lane];
        const float* __restrict__ Wcb = Wmat + cb * 32;
#pragma unroll
        for (int q = 0; q < 8; ++q) a4[q] = make_float4(0.f, 0.f, 0.f, 0.f);
#pragma unroll 2
        for (int kq = 0; kq < 32; ++kq) {
            const float4 hv = hsq(sm, myrow, kq);
#pragma unroll
            for (int q = 0; q < 8; ++q) {
                float4 w0 = *(const float4*)&Wcb[(4 * kq + 0) * FD + 4 * q];
                float4 w1 = *(const float4*)&Wcb[(4 * kq + 1) * FD + 4 * q];
                float4 w2 = *(const float4*)&Wcb[(4 * kq + 2) * FD + 4 * q];
                float4 w3 = *(const float4*)&Wcb[(4 * kq + 3) * FD + 4 * q];
                a4[q].x += hv.x * w0.x + hv.y * w1.x + hv.z * w2.x + hv.w * w3.x;
                a4[q].y += hv.x * w0.y + hv.y * w1.y + hv.z * w2.y + hv.w * w3.y;
                a4[q].z += hv.x * w0.z + hv.y * w1.z + hv.z * w2.z + hv.w * w3.z;
                a4[q].w += hv.x * w0.w + hv.y * w1.w + hv.z * w2.w + hv.w * w3.w;
            }
        }
    }
    __syncthreads();   // ALL reads of hs complete before any write
    // ---- GEMM phase B (write back, in place) ----
    if (gact) {
#pragma unroll
        for (int q = 0; q < 8; ++q)
            hsq(sm, myrow, cb * 8 + q) = a4[q];
    }
    __syncthreads();   // publishes hs = dvv ⊙ (X @ W)

    // ---- conv + relu + fused score matvec (pure-add gather) ----
    const float4 b4  = *(const float4*)&bias[4 * f4];
    const float4 wp4 = *(const float4*)&Wp[4 * f4];
    float4 hreg[NPS];
#pragma unroll
    for (int c = 0; c < NPS; ++c) {
        const int v = sm.anode[c * NSL + s];
        const float dv_ = sm.dvv[v];
        float4 S = hsq(sm, v, f4);                 // scaled self term
        const int e0 = sm.rp[v], e1 = sm.rp[v + 1];
        int e = e0;
        int ea = (e0 + 3) & ~3;                     // align head
        if (ea > e1) ea = e1;
        for (; e < ea; ++e) {
            float4 hu = hsq(sm, sm.colb[e], f4);
            S.x += hu.x; S.y += hu.y; S.z += hu.z; S.w += hu.w;
        }
        for (; e + 4 <= e1; e += 4) {
            unsigned p = *(const unsigned*)&sm.colb[e];
            int u0 = p & 255, u1 = (p >> 8) & 255;
            int u2 = (p >> 16) & 255, u3 = p >> 24;
            float4 h0 = hsq(sm, u0, f4);
            float4 h1 = hsq(sm, u1, f4);
            float4 h2 = hsq(sm, u2, f4);
            float4 h3 = hsq(sm, u3, f4);
            S.x += h0.x + h1.x + h2.x + h3.x;
            S.y += h0.y + h1.y + h2.y + h3.y;
            S.z += h0.z + h1.z + h2.z + h3.z;
            S.w += h0.w + h1.w + h2.w + h3.w;
        }
        for (; e < e1; ++e) {
            float4 hu = hsq(sm, sm.colb[e], f4);
            S.x += hu.x; S.y += hu.y; S.z += hu.z; S.w += hu.w;
        }
        float4 acc;
        acc.x = fmaxf(S.x * dv_ + b4.x, 0.f);
        acc.y = fmaxf(S.y * dv_ + b4.y, 0.f);
        acc.z = fmaxf(S.z * dv_ + b4.z, 0.f);
        acc.w = fmaxf(S.w * dv_ + b4.w, 0.f);
        hreg[c] = acc;
        // score partial: dot(h[v], Wp) reduced across the 32 f4 lanes
        float p = acc.x * wp4.x + acc.y * wp4.y + acc.z * wp4.z + acc.w * wp4.w;
        p += __shfl_xor(p, 1);
        p += __shfl_xor(p, 2);
        p += __shfl_xor(p, 4);
        p += __shfl_xor(p, 8);
        p += __shfl_xor(p, 16);
        if (f4 == 0) sm.sw[v] = p;
    }
    __syncthreads();

    // ---- score conv: TPN threads per active node ----
    {
        const int i = tid / TPN, sub = tid % TPN;
        const int v = sm.anode[i];
        const float dv_ = sm.dvv[v];
        float part = 0.f;
        const int e1 = sm.rp[v + 1];
        for (int e = sm.rp[v] + sub; e < e1; e += TPN) {
            int u = sm.colb[e];
            part += sm.dvv[u] * sm.sw[u];
        }
#pragma unroll
        for (int o = 1; o < TPN; o <<= 1) part += __shfl_xor(part, o);
        if (sub == 0) {
            float acc = sm.sw[v] * dv_ * dv_ + bpp[0] + dv_ * part;
            sm.sf[v] = acc;        // by node id (for tanh later)
            sm.svv[i] = acc;       // by active index (for sort)
        }
    }
    __syncthreads();

    // ---- bitonic sort of NACT active elements, registers + shuffles ----
    // comparator: value desc, node-id asc  (= jax.lax.top_k semantics)
    float v_ = 0.f;
    int   id_ = 0;
    if (tid < NACT) { v_ = sm.svv[tid]; id_ = sm.anode[tid]; }
#pragma unroll
    for (int k = 2; k <= NACT; k <<= 1) {
#pragma unroll
        for (int j = k >> 1; j > 0; j >>= 1) {
            if (j < 64) {
                if (tid < NACT) {
                    float vp = __shfl_xor(v_, j);
                    int  idp = __shfl_xor(id_, j);
                    bool up    = ((tid & k) == 0);
                    bool lower = ((tid & j) == 0);
                    bool g = (v_ > vp) || (v_ == vp && id_ < idp);
                    if (g != (lower == up)) { v_ = vp; id_ = idp; }
                }
            } else {
                if (tid < NACT) { sm.svv[tid] = v_; sm.si[tid] = id_; }
                __syncthreads();
                if (tid < NACT) {
                    int p = tid ^ j;
                    float vp = sm.svv[p];
                    int  idp = sm.si[p];
                    bool up    = ((tid & k) == 0);
                    bool lower = ((tid & j) == 0);
                    bool g = (v_ > vp) || (v_ == vp && id_ < idp);
                    if (g != (lower == up)) { v_ = vp; id_ = idp; }
                }
                __syncthreads();
            }
        }
    }
    if (tid < NPG) sm.kept[tid] = 0;
    __syncthreads();
    if (tid < K) {
        sm.kept[id_] = 1;
        sm.th[id_] = tanhf(sm.sf[id_]);
    }
    __syncthreads();

    // ---- next level's dinv (needs kept; gate reads it for the prescale) ----
    if (!LAST) {
        const int n = tid >> 2, sub = tid & 3;
        int cnti = 0;
        const int kpn = sm.kept[n];
        if (kpn) {
            const int e1 = sm.rp[n + 1];
            for (int e = sm.rp[n] + sub; e < e1; e += 4)
                cnti += sm.kept[sm.colb[e]];
        }
        cnti += __shfl_xor(cnti, 1);
        cnti += __shfl_xor(cnti, 2);
        if (sub == 0) sm.dvv[n] = kpn ? rsqrtf(1.f + (float)cnti) : 0.f;
        __syncthreads();
    }

    // ---- tanh-gate: hs[v] <- dvv_next[v] * h[v]*tanh(s) (0 for dropped);
    //      readout partials use the UNSCALED gated value ----
    float4 mx4 = make_float4(NEG_INF, NEG_INF, NEG_INF, NEG_INF);
    float4 sm4 = make_float4(0.f, 0.f, 0.f, 0.f);
#pragma unroll
    for (int c = 0; c < NPS; ++c) {
        const int v = sm.anode[c * NSL + s];
        const int kp = sm.kept[v];
        const float tg = kp ? sm.th[v] : 0.f;
        float4 val;
        val.x = hreg[c].x * tg;
        val.y = hreg[c].y * tg;
        val.z = hreg[c].z * tg;
        val.w = hreg[c].w * tg;
        if (!LAST) {
            const float dn = sm.dvv[v];     // 0 for dropped -> zeros row
            float4 st;
            st.x = val.x * dn; st.y = val.y * dn;
            st.z = val.z * dn; st.w = val.w * dn;
            hsq(sm, v, f4) = st;
        }
        if (kp) {
            mx4.x = fmaxf(mx4.x, val.x);
            mx4.y = fmaxf(mx4.y, val.y);
            mx4.z = fmaxf(mx4.z, val.z);
            mx4.w = fmaxf(mx4.w, val.w);
        }
        sm4.x += val.x; sm4.y += val.y; sm4.z += val.z; sm4.w += val.w;
    }
    mx4.x = fmaxf(mx4.x, __shfl_xor(mx4.x, 32)); sm4.x += __shfl_xor(sm4.x, 32);
    mx4.y = fmaxf(mx4.y, __shfl_xor(mx4.y, 32)); sm4.y += __shfl_xor(sm4.y, 32);
    mx4.z = fmaxf(mx4.z, __shfl_xor(mx4.z, 32)); sm4.z += __shfl_xor(sm4.z, 32);
    mx4.w = fmaxf(mx4.w, __shfl_xor(mx4.w, 32)); sm4.w += __shfl_xor(sm4.w, 32);
    if ((tid & 63) < 32) {
        *(float4*)&sm.red_mx[wv_][4 * f4] = mx4;
        *(float4*)&sm.red_sm[wv_][4 * f4] = sm4;
    }
    __syncthreads();
    if (tid < FD) {
        float mx = NEG_INF, smv = 0.f;
#pragma unroll
        for (int i = 0; i < 16; ++i) {
            mx = fmaxf(mx, sm.red_mx[i][tid]);
            smv += sm.red_sm[i][tid];
        }
        sm.zacc[tid] += mx;
        sm.zacc[FD + tid] += smv / (float)K;
    }
    // ---- update active set for next level ----
    if (tid < K) sm.anode[tid] = id_;
    __syncthreads();
}

// ---------------------------------------------------------------------------
// Fully-fused kernel: one 1024-thread block per graph does CSR build, all
// 3 GCN+pool levels, readout, and the final MLP + log_softmax.
// ---------------------------------------------------------------------------
__global__ __launch_bounds__(1024)
void k_mega(const float* __restrict__ x, const int* __restrict__ ei,
            const float* __restrict__ W1, const float* __restrict__ b1,
            const float* __restrict__ Wp1, const float* __restrict__ bp1,
            const float* __restrict__ W2, const float* __restrict__ b2,
            const float* __restrict__ Wp2, const float* __restrict__ bp2,
            const float* __restrict__ W3, const float* __restrict__ b3,
            const float* __restrict__ Wp3, const float* __restrict__ bp3,
            const float* __restrict__ Wl1, const float* __restrict__ bl1,
            const float* __restrict__ Wl2, const float* __restrict__ bl2,
            const float* __restrict__ Wl3, const float* __restrict__ bl3,
            float* __restrict__ out) {
    __shared__ SM sm;
    const int g = blockIdx.x, tid = threadIdx.x;
    const int gbase = g * NPG, ebase = g * EPG;
    const int f4 = tid & 31, s = tid >> 5;

    // ---- read this block's edges once (coalesced) ----
    int myd[4], mys[4];
#pragma unroll
    for (int i = 0; i < 4; ++i) {
        int e = ebase + tid + i * 1024;
        myd[i] = ei[NE + e] - gbase;
        mys[i] = ei[e] - gbase;
    }

    // ---- CSR-by-dst build: count -> (L1 dinv from degree) -> scan -> scatter
    if (tid < NPG) sm.si[tid] = 0;
    __syncthreads();
#pragma unroll
    for (int i = 0; i < 4; ++i) atomicAdd(&sm.si[myd[i]], 1);
    __syncthreads();
    int vincl = 0, cnt = 0;
    if (tid < NPG) {
        cnt = sm.si[tid];
        sm.dvv[tid] = rsqrtf(1.f + (float)cnt);     // level-1 dinv, for free
        vincl = cnt;
        const int lane = tid & 63;
#pragma unroll
        for (int o = 1; o < 64; o <<= 1) {
            int n = __shfl_up(vincl, o);
            if (lane >= o) vincl += n;
        }
        if (lane == 63) sm.wsum[tid >> 6] = vincl;
    }
    __syncthreads();
    if (tid < NPG) {
        int base = 0;
        for (int w = 0; w < (tid >> 6); ++w) base += sm.wsum[w];
        int excl = base + vincl - cnt;
        sm.rp[tid] = excl;
        sm.kept[tid] = excl;
        if (tid == 0) sm.rp[NPG] = EPG;
        sm.anode[tid] = tid;
        sm.zacc[tid] = 0.f;                         // 2*FD == NPG
    }
    __syncthreads();
#pragma unroll
    for (int i = 0; i < 4; ++i) {
        int p = atomicAdd(&sm.kept[myd[i]], 1);
        sm.colb[p] = (unsigned char)mys[i];         // LOCAL src id as byte
    }
    // ---- stage x -> LDS (swizzled, PRESCALED by level-1 dinv) ----
    for (int r = s; r < NPG; r += NSL) {
        const float d = sm.dvv[r];
        float4 xv = *(const float4*)&x[((size_t)(gbase + r)) * FD + 4 * f4];
        xv.x *= d; xv.y *= d; xv.z *= d; xv.w *= d;
        hsq(sm, r, f4) = xv;
    }
    __syncthreads();   // colb + hs + state visible block-wide

    do_level<256, false>(sm, W1, b1, Wp1, bp1, tid);
    do_level<128, false>(sm, W2, b2, Wp2, bp2, tid);
    do_level<64,  true >(sm, W3, b3, Wp3, bp3, tid);

    // ---- final MLP + log_softmax (split-k over sub-threads) ----
    {   // layer 1: 128 outs, 4 subs over k=256
        const int o = tid >> 2, sub = tid & 3;
        if (tid < 512) {
            float a = 0.f;
            for (int k = sub; k < 256; k += 4) a += sm.zacc[k] * Wl1[k * 128 + o];
            a += __shfl_xor(a, 1);
            a += __shfl_xor(a, 2);
            if (sub == 0) sm.sw[o] = fmaxf(a + bl1[o], 0.f);
        }
    }
    __syncthreads();
    {   // layer 2: 64 outs, 4 subs over k=128
        const int o = tid >> 2, sub = tid & 3;
        if (tid < 256) {
            float a = 0.f;
            for (int k = sub; k < 128; k += 4) a += sm.sw[k] * Wl2[k * 64 + o];
            a += __shfl_xor(a, 1);
            a += __shfl_xor(a, 2);
            if (sub == 0) sm.sf[o] = fmaxf(a + bl2[o], 0.f);
        }
    }
    __syncthreads();
    {   // layer 3: 10 outs, 8 subs over k=64
        const int o = tid >> 3, sub = tid & 7;
        if (tid < 8 * NC) {
            float a = 0.f;
            for (int k = sub; k < 64; k += 8) a += sm.sf[k] * Wl3[k * NC + o];
            a += __shfl_xor(a, 1);
            a += __shfl_xor(a, 2);
            a += __shfl_xor(a, 4);
            if (sub == 0) sm.svv[o] = a + bl3[o];
        }
    }
    __syncthreads();
    if (tid == 0) {
        float m = sm.svv[0];
        for (int c = 1; c < NC; ++c) m = fmaxf(m, sm.svv[c]);
        float se = 0.f;
        for (int c = 0; c < NC; ++c) se += expf(sm.svv[c] - m);
        float lse = m + logf(se);
        for (int c = 0; c < NC; ++c) out[g * NC + c] = sm.svv[c] - lse;
    }
}

// ---------------------------------------------------------------------------
extern "C" void kernel_launch(void* const* d_in, const int* in_sizes, int n_in,
                              void* d_out, int out_size, void* d_ws, size_t ws_size,
                              hipStream_t stream) {
    const float* x   = (const float*)d_in[0];
    const int*   ei  = (const int*)d_in[1];
    const float* W1  = (const float*)d_in[3];
    const float* b1  = (const float*)d_in[4];
    const float* Wp1 = (const float*)d_in[5];
    const float* bp1 = (const float*)d_in[6];
    const float* W2  = (const float*)d_in[7];
    const float* b2  = (const float*)d_in[8];
    const float* Wp2 = (const float*)d_in[9];
    const float* bp2 = (const float*)d_in[10];
    const float* W3  = (const float*)d_in[11];
    const float* b3  = (const float*)d_in[12];
    const float* Wp3 = (const float*)d_in[13];
    const float* bp3 = (const float*)d_in[14];
    const float* Wl1 = (const float*)d_in[15];
    const float* bl1 = (const float*)d_in[16];
    const float* Wl2 = (const float*)d_in[17];
    const float* bl2 = (const float*)d_in[18];
    const float* Wl3 = (const float*)d_in[19];
    const float* bl3 = (const float*)d_in[20];
    float* out = (float*)d_out;

    k_mega<<<NB, 1024, 0, stream>>>(x, ei,
                                    W1, b1, Wp1, bp1,
                                    W2, b2, Wp2, bp2,
                                    W3, b3, Wp3, bp3,
                                    Wl1, bl1, Wl2, bl2, Wl3, bl3, out);
}